// Round 21
// baseline (3523.856 us; speedup 1.0000x reference)
//
#include <hip/hip_runtime.h>
#include <math.h>

typedef unsigned short u16;
typedef __attribute__((ext_vector_type(8))) short bf8;     // 8 x bf16 (raw bits)
typedef __attribute__((ext_vector_type(4))) float f4;

#define DEV static __device__ __forceinline__

DEV u16 f2b(float f){
  unsigned u = __builtin_bit_cast(unsigned, f);
  u += 0x7fffu + ((u >> 16) & 1u);          // round-to-nearest-even
  return (u16)(u >> 16);
}
DEV float b2f(u16 h){
  unsigned u = ((unsigned)h) << 16;
  return __builtin_bit_cast(float, u);
}
DEV bf8 pk8(f4 lo, f4 hi){                  // 8 x f32 -> 8 x bf16 (RNE)
  bf8 r;
  r[0]=(short)f2b(lo[0]); r[1]=(short)f2b(lo[1]);
  r[2]=(short)f2b(lo[2]); r[3]=(short)f2b(lo[3]);
  r[4]=(short)f2b(hi[0]); r[5]=(short)f2b(hi[1]);
  r[6]=(short)f2b(hi[2]); r[7]=(short)f2b(hi[3]);
  return r;
}

#define BATCH  8
#define NTOK   581
#define NPAD   640
#define DIM    768
#define DFF    3072
#define NHEAD  12
#define HDIM   64
#define NLAYER 12
#define MTOK   (BATCH*NTOK)     /* 4648 */
#define MPAD2  4736             /* 37*128 = 74*64 */
#define MCONV  (BATCH*576)      /* 4608 = 72*64 */
#define ATTN_SCALE 0.125f
#define BHEADS (BATCH*NHEAD)    /* 96 */
#define QSZ    ((long long)BHEADS*NPAD*HDIM)

enum { EPI_CONV=0, EPI_QKV, EPI_PROJ, EPI_GELU, EPI_FC2 };

// bijective XCD-chunked swizzle (m204): contiguous tile ids cluster per XCD
DEV int xcdswz(int lin, int n){
  int q = n >> 3, r = n & 7;
  int x = lin & 7, o = lin >> 3;
  return (x < r ? x*(q+1) : r*(q+1) + (x - r)*q) + o;
}

// ---- BMxBN tile GEMM, BK=32, reg-staged dbuf, async-split, 1 barrier/K-step ----
// C = A(MxK,row,bf16) * B(NxK,row,F32)^T -- B converted to bf16 in-register at
// staging (bit-identical to a separate cvt pass). M=gy*BM, N=gx*BN, K%64==0.
// EPI_QKV: aux = rope table (cos[0:384], sin[384:768]); RoPE fused via lane-pair shfl.
template<int EPI, int BM, int BN, int NWAVE>
__global__ __launch_bounds__(NWAVE*64) void gemmRS(
    const u16* __restrict__ A, int lda,
    const float* __restrict__ B, int ldb, int K,
    const float* __restrict__ bias,
    const float* __restrict__ aux,
    float* __restrict__ Cf,
    u16* __restrict__ Cb)
{
  constexpr int NT = NWAVE * 64;
  constexpr int SR = NT / 4;                        // staging rows per slot
  constexpr int AL = BM / SR, BL = BN / SR;         // loads per thread
  constexpr int WROWS = (NWAVE == 8) ? 4 : 2;
  constexpr int WCOLS = NWAVE / WROWS;
  constexpr int TR = BM / WROWS, TC = BN / WCOLS;   // wave output tile
  constexpr int MR = TR / 16, NR = TC / 16;
  const int gx = gridDim.x;
  const int lin = blockIdx.y * gx + blockIdx.x;
  const int tix = xcdswz(lin, gx * gridDim.y);
  const int bm = (tix / gx) * BM, bn = (tix % gx) * BN;
  __shared__ __attribute__((aligned(16))) u16 As[2][BM][40];
  __shared__ __attribute__((aligned(16))) u16 Bs[2][BN][40];
  const int tid  = threadIdx.x;
  const int lane = tid & 63, wid = tid >> 6;
  const int wr = wid % WROWS, wc = wid / WROWS;
  const int srow = tid >> 2, scol = (tid & 3) * 8;  // staging coords
  const u16* gA[AL]; const float* gB[BL];
  #pragma unroll
  for (int i = 0; i < AL; ++i) gA[i] = A + (long long)(bm + i*SR + srow) * lda + scol;
  #pragma unroll
  for (int i = 0; i < BL; ++i) gB[i] = B + (long long)(bn + i*SR + srow) * ldb + scol;
  const int frow = lane & 15, quad = lane >> 4, fk = quad * 8;

  f4 acc[MR][NR] = {};
  const int T = K >> 5;                             // even (K%64==0)

  bf8 xA[AL], yA[AL];
  f4  xBl[BL], xBh[BL], yBl[BL], yBh[BL];
  auto loadX = [&](int kt){
    #pragma unroll
    for (int i = 0; i < AL; ++i) xA[i] = *(const bf8*)(gA[i] + kt*32);
    #pragma unroll
    for (int i = 0; i < BL; ++i){
      xBl[i] = *(const f4*)(gB[i] + kt*32);
      xBh[i] = *(const f4*)(gB[i] + kt*32 + 4);
    }
  };
  auto loadY = [&](int kt){
    #pragma unroll
    for (int i = 0; i < AL; ++i) yA[i] = *(const bf8*)(gA[i] + kt*32);
    #pragma unroll
    for (int i = 0; i < BL; ++i){
      yBl[i] = *(const f4*)(gB[i] + kt*32);
      yBh[i] = *(const f4*)(gB[i] + kt*32 + 4);
    }
  };
  auto storeX = [&](int buf){
    #pragma unroll
    for (int i = 0; i < AL; ++i) *(bf8*)&As[buf][i*SR + srow][scol] = xA[i];
    #pragma unroll
    for (int i = 0; i < BL; ++i) *(bf8*)&Bs[buf][i*SR + srow][scol] = pk8(xBl[i], xBh[i]);
  };
  auto storeY = [&](int buf){
    #pragma unroll
    for (int i = 0; i < AL; ++i) *(bf8*)&As[buf][i*SR + srow][scol] = yA[i];
    #pragma unroll
    for (int i = 0; i < BL; ++i) *(bf8*)&Bs[buf][i*SR + srow][scol] = pk8(yBl[i], yBh[i]);
  };
  auto compute = [&](int buf){
    bf8 af[MR], bf[NR];
    #pragma unroll
    for (int m = 0; m < MR; ++m)
      af[m] = *(const bf8*)&As[buf][wr*TR + m*16 + frow][fk];
    #pragma unroll
    for (int n = 0; n < NR; ++n)
      bf[n] = *(const bf8*)&Bs[buf][wc*TC + n*16 + frow][fk];
    #pragma unroll
    for (int m = 0; m < MR; ++m)
    #pragma unroll
    for (int n = 0; n < NR; ++n)
      acc[m][n] = __builtin_amdgcn_mfma_f32_16x16x32_bf16(af[m], bf[n], acc[m][n], 0, 0, 0);
  };

  // prologue: tile0 -> X, tile1 -> Y, write tile0
  loadX(0); loadY(1);
  storeX(0);
  __syncthreads();

  for (int t = 0; t < T; t += 2){
    // even half: compute tile t (buf0); stage Y(t+1)->buf1; load X <- t+2
    if (t + 2 < T) loadX(t + 2);
    storeY(1);
    compute(0);
    __syncthreads();
    // odd half: compute tile t+1 (buf1); stage X(t+2)->buf0; load Y <- t+3
    if (t + 3 < T) loadY(t + 3);
    if (t + 2 < T) storeX(0);
    compute(1);
    __syncthreads();
  }

  #pragma unroll
  for (int mi = 0; mi < MR; ++mi)
  #pragma unroll
  for (int ni = 0; ni < NR; ++ni){
    f4 v = acc[mi][ni];
    int col = bn + wc*TC + ni*16 + frow;
    int r0  = bm + wr*TR + mi*16 + quad*4;
    #pragma unroll
    for (int j = 0; j < 4; ++j){
      int m = r0 + j;
      float val = v[j];
      if constexpr (EPI == EPI_CONV){
        int b = m / 576, p = m % 576;
        Cf[((long long)b*NTOK + 5 + p)*DIM + col] = val + bias[col];
      } else if constexpr (EPI == EPI_QKV){
        if (m < MTOK){                              // uniform across lane pairs
          int b = m / NTOK, tt = m % NTOK;
          int which = col / DIM, rem = col % DIM;
          int h = rem / HDIM, hd = rem % HDIM;
          float x = val + bias[col];
          if (which == 0) x *= ATTN_SCALE;          // scale commutes with rotation
          if (which < 2 && tt >= 5){                // fused RoPE (pair-uniform branch)
            float po = __shfl_xor(x, 1);            // partner of the (even,odd) pair
            int p = tt - 5;
            int f = (hd & 31) >> 1;
            int pc = (hd < 32) ? (p % 24) : (p / 24);
            float c = aux[pc*16 + f];
            float s = aux[384 + pc*16 + f];
            x = (hd & 1) ? (po*s + x*c) : (x*c - po*s);
          }
          long long bh = (long long)(b*NHEAD + h);
          if (which == 2)      // V stored transposed: VT[bh][d][t]
            Cb[2*QSZ + (bh*HDIM + hd)*NPAD + tt] = f2b(x);
          else
            Cb[(long long)which*QSZ + (bh*NPAD + tt)*HDIM + hd] = f2b(x);
        }
      } else if constexpr (EPI == EPI_PROJ || EPI == EPI_FC2){
        if (m < MTOK)
          Cf[(long long)m*DIM + col] += aux[col] * (val + bias[col]);
      } else if constexpr (EPI == EPI_GELU){
        float x = val + bias[col];
        float g = 0.5f * x * (1.0f + erff(x * 0.70710678118f));
        Cb[(long long)m*DFF + col] = f2b(g);
      }
    }
  }
}

// -------- flash attention: 128 q-rows of one (b,h) per block; 4 waves x 2 bands --------
// Grid: 1D 480 blocks; lid&7 = XCD (round-robin heuristic): 12 heads/XCD -> K/V 1.9MB L2-fits.
// Q,K: [bh][NPAD][64] bf16 (Q pre-scaled+roped); VT: [bh][64][NPAD]; pads zero.
// Softmax: per-lane partial row-sums reduced across lanes once at the end;
// cross-lane max computed only inside the (rare) rescale branch.
__global__ __launch_bounds__(256) void flash_k(
    const u16* __restrict__ Q, const u16* __restrict__ K,
    const u16* __restrict__ VT, u16* __restrict__ obuf)
{
  const int lid = blockIdx.x;
  const int xcd = lid & 7, slot = lid >> 3;         // slot in [0,60)
  const int bh = xcd * 12 + slot / 5;
  const int qb = slot % 5;                          // 128-row q block
  const int b = bh / NHEAD, h = bh % NHEAD;
  const int tid = threadIdx.x, lane = tid & 63, w = tid >> 6;
  const int frow = lane & 15, quad = lane >> 4;
  __shared__ u16 P[4][2][16][80];
  const u16* Qb = Q  + (long long)bh * NPAD * HDIM;
  const u16* Kb = K  + (long long)bh * NPAD * HDIM;
  const u16* Vb = VT + (long long)bh * HDIM * NPAD;
  bf8 qa0[2], qa1[2];
  #pragma unroll
  for (int bd = 0; bd < 2; ++bd){
    const u16* qr = &Qb[(qb*128 + bd*64 + w*16 + frow)*HDIM + quad*8];
    qa0[bd] = *(const bf8*)qr;
    qa1[bd] = *(const bf8*)(qr + 32);
  }
  f4 o[2][4] = {};
  float m[2][4], lp[2][4];
  #pragma unroll
  for (int bd = 0; bd < 2; ++bd)
  #pragma unroll
  for (int j = 0; j < 4; ++j){ m[bd][j] = -1e30f; lp[bd][j] = 0.0f; }

  // K fragments for current tile (prefetched one tile ahead)
  bf8 kb0[4], kb1[4];
  #pragma unroll
  for (int n = 0; n < 4; ++n){
    const u16* kr = &Kb[(n*16 + frow)*HDIM + quad*8];
    kb0[n] = *(const bf8*)kr;
    kb1[n] = *(const bf8*)(kr + 32);
  }

  for (int kt = 0; kt < NPAD/64; ++kt){
    // V loads issued early (covered by softmax VALU)
    bf8 vb0[4], vb1[4];
    #pragma unroll
    for (int n = 0; n < 4; ++n){
      const u16* vr = &Vb[(n*16 + frow)*NPAD + kt*64 + quad*8];
      vb0[n] = *(const bf8*)vr;
      vb1[n] = *(const bf8*)(vr + 32);
    }
    // S = Q·K^T for both bands from shared K frags
    f4 s[2][4];
    __builtin_amdgcn_s_setprio(1);
    #pragma unroll
    for (int n = 0; n < 4; ++n)
    #pragma unroll
    for (int bd = 0; bd < 2; ++bd){
      f4 z = {};
      z        = __builtin_amdgcn_mfma_f32_16x16x32_bf16(qa0[bd], kb0[n], z, 0, 0, 0);
      s[bd][n] = __builtin_amdgcn_mfma_f32_16x16x32_bf16(qa1[bd], kb1[n], z, 0, 0, 0);
    }
    __builtin_amdgcn_s_setprio(0);
    // prefetch K for kt+1 (covered by softmax + PV)
    if (kt + 1 < NPAD/64){
      #pragma unroll
      for (int n = 0; n < 4; ++n){
        const u16* kr = &Kb[((kt+1)*64 + n*16 + frow)*HDIM + quad*8];
        kb0[n] = *(const bf8*)kr;
        kb1[n] = *(const bf8*)(kr + 32);
      }
    }
    if (kt == NPAD/64 - 1){                         // mask invalid k-cols
      #pragma unroll
      for (int n = 0; n < 4; ++n){
        int kcol = kt*64 + n*16 + frow;
        if (kcol >= NTOK){
          #pragma unroll
          for (int bd = 0; bd < 2; ++bd)
            s[bd][n][0] = s[bd][n][1] = s[bd][n][2] = s[bd][n][3] = -1e30f;
        }
      }
    }
    #pragma unroll
    for (int bd = 0; bd < 2; ++bd){
      // per-lane tile max; cross-lane reduce only if a rescale might be needed
      float vmax[4];
      int need = 0;
      #pragma unroll
      for (int j = 0; j < 4; ++j){
        vmax[j] = fmaxf(fmaxf(s[bd][0][j], s[bd][1][j]), fmaxf(s[bd][2][j], s[bd][3][j]));
        need |= (vmax[j] > m[bd][j] + 8.0f) ? 1 : 0;
      }
      if (__any(need)){                             // defer-max: rescale only on growth >8
        #pragma unroll
        for (int j = 0; j < 4; ++j){
          float v = vmax[j];
          v = fmaxf(v, __shfl_xor(v, 1));  v = fmaxf(v, __shfl_xor(v, 2));
          v = fmaxf(v, __shfl_xor(v, 4));  v = fmaxf(v, __shfl_xor(v, 8));
          float mn = fmaxf(m[bd][j], v);
          float sc = __expf(m[bd][j] - mn);
          m[bd][j] = mn;
          lp[bd][j] *= sc;                          // per-lane partial sum rescales too
          #pragma unroll
          for (int n = 0; n < 4; ++n) o[bd][n][j] *= sc;
        }
      }
      #pragma unroll
      for (int n = 0; n < 4; ++n){
        #pragma unroll
        for (int j = 0; j < 4; ++j){
          float p = __expf(s[bd][n][j] - m[bd][j]);   // bounded by e^8
          lp[bd][j] += p;                             // deferred cross-lane reduce
          P[w][bd][quad*4 + j][n*16 + frow] = f2b(p);
        }
      }
      bf8 pa0 = *(const bf8*)&P[w][bd][frow][quad*8];
      bf8 pa1 = *(const bf8*)&P[w][bd][frow][quad*8 + 32];
      __builtin_amdgcn_s_setprio(1);
      #pragma unroll
      for (int n = 0; n < 4; ++n){
        o[bd][n] = __builtin_amdgcn_mfma_f32_16x16x32_bf16(pa0, vb0[n], o[bd][n], 0, 0, 0);
        o[bd][n] = __builtin_amdgcn_mfma_f32_16x16x32_bf16(pa1, vb1[n], o[bd][n], 0, 0, 0);
      }
      __builtin_amdgcn_s_setprio(0);
    }
  }
  // final cross-lane reduce of the row sums (once, instead of per-kt)
  #pragma unroll
  for (int bd = 0; bd < 2; ++bd)
  #pragma unroll
  for (int j = 0; j < 4; ++j){
    float v = lp[bd][j];
    v += __shfl_xor(v, 1); v += __shfl_xor(v, 2);
    v += __shfl_xor(v, 4); v += __shfl_xor(v, 8);
    lp[bd][j] = v;
  }
  #pragma unroll
  for (int bd = 0; bd < 2; ++bd)
  #pragma unroll
  for (int j = 0; j < 4; ++j){
    int t = qb*128 + bd*64 + w*16 + quad*4 + j;
    if (t < NTOK){
      float inv = 1.0f / lp[bd][j];
      #pragma unroll
      for (int n = 0; n < 4; ++n)
        obuf[((long long)b*NTOK + t)*DIM + h*HDIM + n*16 + frow] = f2b(o[bd][n][j] * inv);
    }
  }
}

// LayerNorm over D=768 per row; writes bf16 (F32OUT=0) or f32 (F32OUT=1).
template<int F32OUT>
__global__ __launch_bounds__(256) void ln_k(const float* __restrict__ x,
    const float* __restrict__ s, const float* __restrict__ b,
    u16* __restrict__ ob, float* __restrict__ of)
{
  const long long row = blockIdx.x;
  const float* xr = x + row * DIM;
  const int t = threadIdx.x;
  float v0 = xr[t], v1 = xr[t + 256], v2 = xr[t + 512];
  float sum = v0 + v1 + v2;
  #pragma unroll
  for (int o = 32; o; o >>= 1) sum += __shfl_down(sum, o);
  __shared__ float r1[4], r2[4];
  const int lane = t & 63, w = t >> 6;
  if (lane == 0) r1[w] = sum;
  __syncthreads();
  float mu = (r1[0] + r1[1] + r1[2] + r1[3]) * (1.0f / DIM);
  float d0 = v0 - mu, d1 = v1 - mu, d2 = v2 - mu;
  float vs = d0*d0 + d1*d1 + d2*d2;
  #pragma unroll
  for (int o = 32; o; o >>= 1) vs += __shfl_down(vs, o);
  if (lane == 0) r2[w] = vs;
  __syncthreads();
  float inv = 1.0f / sqrtf((r2[0] + r2[1] + r2[2] + r2[3]) * (1.0f / DIM) + 1e-6f);
  if constexpr (F32OUT){
    float* orow = of + row * DIM;
    orow[t]       = d0 * inv * s[t]       + b[t];
    orow[t + 256] = d1 * inv * s[t + 256] + b[t + 256];
    orow[t + 512] = d2 * inv * s[t + 512] + b[t + 512];
  } else {
    u16* orow = ob + row * DIM;
    orow[t]       = f2b(d0 * inv * s[t]       + b[t]);
    orow[t + 256] = f2b(d1 * inv * s[t + 256] + b[t + 256]);
    orow[t + 512] = f2b(d2 * inv * s[t + 512] + b[t + 512]);
  }
}

__global__ void ropetab_k(const float* __restrict__ periods, float* __restrict__ tab)
{
  int idx = blockIdx.x * blockDim.x + threadIdx.x;
  if (idx >= 24 * 16) return;
  int c = idx >> 4, f = idx & 15;
  float fr = 6.283185307179586f / periods[f];
  float a = (float)c * fr;
  tab[idx]       = cosf(a);
  tab[384 + idx] = sinf(a);
}

__global__ void initx_k(float* __restrict__ x, const float* __restrict__ cls,
                        const float* __restrict__ stor)
{
  int idx = blockIdx.x * blockDim.x + threadIdx.x;
  if (idx >= BATCH * 5 * DIM) return;
  int d = idx % DIM; int t = (idx / DIM) % 5; int b = idx / (5 * DIM);
  x[((long long)b * NTOK + t) * DIM + d] = (t == 0) ? cls[d] : stor[(t - 1) * DIM + d];
}

__global__ void patch_k(const float* __restrict__ px, u16* __restrict__ Ap)
{
  int idx = blockIdx.x * blockDim.x + threadIdx.x;
  if (idx >= MCONV * DIM) return;
  int k = idx % DIM, m = idx / DIM;
  int b = m / 576, r = m % 576, hp = r / 24, wp = r % 24;
  int c = k / 256, rem = k % 256, p = rem / 16, q = rem % 16;
  float v = px[((((long long)b * 3 + c) * 384) + hp * 16 + p) * 384 + wp * 16 + q];
  Ap[idx] = f2b(v);
}

__global__ void biaseff_k(const float* __restrict__ qb, const float* __restrict__ bm,
                          float* __restrict__ out, int n)
{
  int i = blockIdx.x * blockDim.x + threadIdx.x;
  if (i < n) out[i] = qb[i] * bm[i];
}

extern "C" void kernel_launch(void* const* d_in, const int* in_sizes, int n_in,
                              void* d_out, int out_size, void* d_ws, size_t ws_size,
                              hipStream_t stream)
{
  const float* pixel   = (const float*)d_in[0];
  const float* conv_w  = (const float*)d_in[1];
  const float* conv_b  = (const float*)d_in[2];
  const float* cls     = (const float*)d_in[3];
  const float* stor    = (const float*)d_in[4];
  const float* periods = (const float*)d_in[5];
  const float* ln1s    = (const float*)d_in[6];
  const float* ln1b    = (const float*)d_in[7];
  const float* qkvw    = (const float*)d_in[8];
  const float* qkvb    = (const float*)d_in[9];
  const float* bmask   = (const float*)d_in[10];
  const float* projw   = (const float*)d_in[11];
  const float* projb   = (const float*)d_in[12];
  const float* ls1     = (const float*)d_in[13];
  const float* ln2s    = (const float*)d_in[14];
  const float* ln2b    = (const float*)d_in[15];
  const float* fc1w    = (const float*)d_in[16];
  const float* fc1b    = (const float*)d_in[17];
  const float* fc2w    = (const float*)d_in[18];
  const float* fc2b    = (const float*)d_in[19];
  const float* ls2     = (const float*)d_in[20];
  const float* lnfs    = (const float*)d_in[21];
  const float* lnfb    = (const float*)d_in[22];

  char* wsp = (char*)d_ws;
  auto alloc = [&](long long bytes) -> char* {
    char* p = wsp; wsp += (bytes + 255) & ~255LL; return p;
  };
  float* beff  = (float*)alloc((long long)NLAYER*2304*4);
  float* x     = (float*)alloc((long long)MPAD2*DIM*4);
  u16*   h     = (u16*)  alloc((long long)MPAD2*DIM*2);
  u16*   obuf  = (u16*)  alloc((long long)MPAD2*DIM*2);
  u16*   mlp   = (u16*)  alloc((long long)MPAD2*DFF*2);
  u16*   Ap    = (u16*)  alloc((long long)MCONV*DIM*2);
  u16*   Q     = (u16*)  alloc(QSZ*2*3);
  u16*   Kb    = Q + QSZ;
  u16*   VT    = Q + 2*QSZ;     // V stored transposed [bh][d][t]
  float* tab   = (float*)alloc((long long)2*24*16*4);
  if ((size_t)(wsp - (char*)d_ws) > ws_size) return;  // workspace too small

  biaseff_k<<<(NLAYER*2304 + 255)/256, 256, 0, stream>>>(qkvb, bmask, beff, NLAYER*2304);
  ropetab_k<<<2, 256, 0, stream>>>(periods, tab);
  hipMemsetAsync(Q, 0, (size_t)QSZ*2*3, stream);   // Q/K pad rows, VT pad cols zero

  patch_k<<<(MCONV*DIM + 255)/256, 256, 0, stream>>>(pixel, Ap);
  initx_k<<<(BATCH*5*DIM + 255)/256, 256, 0, stream>>>(x, cls, stor);
  gemmRS<EPI_CONV,64,64,4><<<dim3(DIM/64, MCONV/64), 256, 0, stream>>>(
      Ap, DIM, conv_w, DIM, DIM, conv_b, nullptr, x, nullptr);

  for (int l = 0; l < NLAYER; ++l){
    ln_k<0><<<MTOK, 256, 0, stream>>>(x, ln1s + l*DIM, ln1b + l*DIM, h, nullptr);
    gemmRS<EPI_QKV,128,64,4><<<dim3(2304/64, MPAD2/128), 256, 0, stream>>>(
        h, DIM, qkvw + (long long)l*2304*768, DIM, DIM,
        beff + l*2304, tab, nullptr, Q);
    flash_k<<<dim3(480), 256, 0, stream>>>(Q, Kb, VT, obuf);
    gemmRS<EPI_PROJ,64,64,4><<<dim3(DIM/64, MPAD2/64), 256, 0, stream>>>(
        obuf, DIM, projw + (long long)l*768*768, DIM, DIM,
        projb + l*DIM, ls1 + l*DIM, x, nullptr);
    ln_k<0><<<MTOK, 256, 0, stream>>>(x, ln2s + l*DIM, ln2b + l*DIM, h, nullptr);
    gemmRS<EPI_GELU,128,64,4><<<dim3(DFF/64, MPAD2/128), 256, 0, stream>>>(
        h, DIM, fc1w + (long long)l*3072*768, DIM, DIM,
        fc1b + l*DFF, nullptr, nullptr, mlp);
    gemmRS<EPI_FC2,64,64,4><<<dim3(DIM/64, MPAD2/64), 256, 0, stream>>>(
        mlp, DFF, fc2w + (long long)l*768*3072, DFF, DFF,
        fc2b + l*DIM, ls2 + l*DIM, x, nullptr);
  }
  ln_k<1><<<MTOK, 256, 0, stream>>>(x, lnfs, lnfb, nullptr, (float*)d_out);
}

// Round 22
// 3137.910 us; speedup vs baseline: 1.1230x; 1.1230x over previous
//
#include <hip/hip_runtime.h>
#include <math.h>

typedef unsigned short u16;
typedef __attribute__((ext_vector_type(8))) short bf8;     // 8 x bf16 (raw bits)
typedef __attribute__((ext_vector_type(4))) float f4;

#define DEV static __device__ __forceinline__

DEV u16 f2b(float f){
  unsigned u = __builtin_bit_cast(unsigned, f);
  u += 0x7fffu + ((u >> 16) & 1u);          // round-to-nearest-even
  return (u16)(u >> 16);
}
DEV float b2f(u16 h){
  unsigned u = ((unsigned)h) << 16;
  return __builtin_bit_cast(float, u);
}

#define BATCH  8
#define NTOK   581
#define NPAD   640
#define DIM    768
#define DFF    3072
#define NHEAD  12
#define HDIM   64
#define NLAYER 12
#define MTOK   (BATCH*NTOK)     /* 4648 */
#define MPAD2  4736             /* 37*128 = 74*64 */
#define MCONV  (BATCH*576)      /* 4608 = 72*64 */
#define ATTN_SCALE 0.125f
#define BHEADS (BATCH*NHEAD)    /* 96 */
#define QSZ    ((long long)BHEADS*NPAD*HDIM)

enum { EPI_CONV=0, EPI_QKV, EPI_PROJ, EPI_GELU, EPI_FC2 };

// bijective XCD-chunked swizzle (m204): contiguous tile ids cluster per XCD
DEV int xcdswz(int lin, int n){
  int q = n >> 3, r = n & 7;
  int x = lin & 7, o = lin >> 3;
  return (x < r ? x*(q+1) : r*(q+1) + (x - r)*q) + o;
}

// ---- BMxBN tile GEMM, BK=32, reg-staged dbuf, async-split, 1 barrier/K-step ----
// C = A(MxK,row) * B(NxK,row)^T. M = gridDim.y*BM, N = gridDim.x*BN, K%64==0.
// EPI_QKV: aux = rope table (cos[0:384], sin[384:768]); RoPE fused via lane-pair shfl.
template<int EPI, int BM, int BN, int NWAVE>
__global__ __launch_bounds__(NWAVE*64) void gemmRS(
    const u16* __restrict__ A, int lda,
    const u16* __restrict__ B, int ldb, int K,
    const float* __restrict__ bias,
    const float* __restrict__ aux,
    float* __restrict__ Cf,
    u16* __restrict__ Cb)
{
  constexpr int NT = NWAVE * 64;
  constexpr int SR = NT / 4;                        // staging rows per slot
  constexpr int AL = BM / SR, BL = BN / SR;         // loads per thread
  constexpr int WROWS = (NWAVE == 8) ? 4 : 2;
  constexpr int WCOLS = NWAVE / WROWS;
  constexpr int TR = BM / WROWS, TC = BN / WCOLS;   // wave output tile
  constexpr int MR = TR / 16, NR = TC / 16;
  const int gx = gridDim.x;
  const int lin = blockIdx.y * gx + blockIdx.x;
  const int tix = xcdswz(lin, gx * gridDim.y);
  const int bm = (tix / gx) * BM, bn = (tix % gx) * BN;
  __shared__ __attribute__((aligned(16))) u16 As[2][BM][40];
  __shared__ __attribute__((aligned(16))) u16 Bs[2][BN][40];
  const int tid  = threadIdx.x;
  const int lane = tid & 63, wid = tid >> 6;
  const int wr = wid % WROWS, wc = wid / WROWS;
  const int srow = tid >> 2, scol = (tid & 3) * 8;  // staging coords
  const u16* gA[AL]; const u16* gB[BL];
  #pragma unroll
  for (int i = 0; i < AL; ++i) gA[i] = A + (long long)(bm + i*SR + srow) * lda + scol;
  #pragma unroll
  for (int i = 0; i < BL; ++i) gB[i] = B + (long long)(bn + i*SR + srow) * ldb + scol;
  const int frow = lane & 15, quad = lane >> 4, fk = quad * 8;

  f4 acc[MR][NR] = {};
  const int T = K >> 5;                             // even (K%64==0)

  bf8 xA[AL], xB[BL], yA[AL], yB[BL];
  auto loadX = [&](int kt){
    #pragma unroll
    for (int i = 0; i < AL; ++i) xA[i] = *(const bf8*)(gA[i] + kt*32);
    #pragma unroll
    for (int i = 0; i < BL; ++i) xB[i] = *(const bf8*)(gB[i] + kt*32);
  };
  auto loadY = [&](int kt){
    #pragma unroll
    for (int i = 0; i < AL; ++i) yA[i] = *(const bf8*)(gA[i] + kt*32);
    #pragma unroll
    for (int i = 0; i < BL; ++i) yB[i] = *(const bf8*)(gB[i] + kt*32);
  };
  auto storeX = [&](int buf){
    #pragma unroll
    for (int i = 0; i < AL; ++i) *(bf8*)&As[buf][i*SR + srow][scol] = xA[i];
    #pragma unroll
    for (int i = 0; i < BL; ++i) *(bf8*)&Bs[buf][i*SR + srow][scol] = xB[i];
  };
  auto storeY = [&](int buf){
    #pragma unroll
    for (int i = 0; i < AL; ++i) *(bf8*)&As[buf][i*SR + srow][scol] = yA[i];
    #pragma unroll
    for (int i = 0; i < BL; ++i) *(bf8*)&Bs[buf][i*SR + srow][scol] = yB[i];
  };
  auto compute = [&](int buf){
    bf8 af[MR], bf[NR];
    #pragma unroll
    for (int m = 0; m < MR; ++m)
      af[m] = *(const bf8*)&As[buf][wr*TR + m*16 + frow][fk];
    #pragma unroll
    for (int n = 0; n < NR; ++n)
      bf[n] = *(const bf8*)&Bs[buf][wc*TC + n*16 + frow][fk];
    #pragma unroll
    for (int m = 0; m < MR; ++m)
    #pragma unroll
    for (int n = 0; n < NR; ++n)
      acc[m][n] = __builtin_amdgcn_mfma_f32_16x16x32_bf16(af[m], bf[n], acc[m][n], 0, 0, 0);
  };

  // prologue: tile0 -> X, tile1 -> Y, write tile0
  loadX(0); loadY(1);
  storeX(0);
  __syncthreads();

  for (int t = 0; t < T; t += 2){
    // even half: compute tile t (buf0); stage Y(t+1)->buf1; load X <- t+2
    if (t + 2 < T) loadX(t + 2);
    storeY(1);
    compute(0);
    __syncthreads();
    // odd half: compute tile t+1 (buf1); stage X(t+2)->buf0; load Y <- t+3
    if (t + 3 < T) loadY(t + 3);
    if (t + 2 < T) storeX(0);
    compute(1);
    __syncthreads();
  }

  #pragma unroll
  for (int mi = 0; mi < MR; ++mi)
  #pragma unroll
  for (int ni = 0; ni < NR; ++ni){
    f4 v = acc[mi][ni];
    int col = bn + wc*TC + ni*16 + frow;
    int r0  = bm + wr*TR + mi*16 + quad*4;
    #pragma unroll
    for (int j = 0; j < 4; ++j){
      int m = r0 + j;
      float val = v[j];
      if constexpr (EPI == EPI_CONV){
        int b = m / 576, p = m % 576;
        Cf[((long long)b*NTOK + 5 + p)*DIM + col] = val + bias[col];
      } else if constexpr (EPI == EPI_QKV){
        if (m < MTOK){                              // uniform across lane pairs
          int b = m / NTOK, tt = m % NTOK;
          int which = col / DIM, rem = col % DIM;
          int h = rem / HDIM, hd = rem % HDIM;
          float x = val + bias[col];
          if (which == 0) x *= ATTN_SCALE;          // scale commutes with rotation
          if (which < 2 && tt >= 5){                // fused RoPE (pair-uniform branch)
            float po = __shfl_xor(x, 1);            // partner of the (even,odd) pair
            int p = tt - 5;
            int f = (hd & 31) >> 1;
            int pc = (hd < 32) ? (p % 24) : (p / 24);
            float c = aux[pc*16 + f];
            float s = aux[384 + pc*16 + f];
            x = (hd & 1) ? (po*s + x*c) : (x*c - po*s);
          }
          long long bh = (long long)(b*NHEAD + h);
          if (which == 2)      // V stored transposed: VT[bh][d][t]
            Cb[2*QSZ + (bh*HDIM + hd)*NPAD + tt] = f2b(x);
          else
            Cb[(long long)which*QSZ + (bh*NPAD + tt)*HDIM + hd] = f2b(x);
        }
      } else if constexpr (EPI == EPI_PROJ || EPI == EPI_FC2){
        if (m < MTOK)
          Cf[(long long)m*DIM + col] += aux[col] * (val + bias[col]);
      } else if constexpr (EPI == EPI_GELU){
        float x = val + bias[col];
        float g = 0.5f * x * (1.0f + erff(x * 0.70710678118f));
        Cb[(long long)m*DFF + col] = f2b(g);
      }
    }
  }
}

// -------- flash attention: 128 q-rows of one (b,h) per block; 4 waves x 2 bands --------
// Grid: 1D 480 blocks; lid&7 = XCD (round-robin heuristic): 12 heads/XCD -> K/V 1.9MB L2-fits.
// Q,K: [bh][NPAD][64] bf16 (Q pre-scaled+roped); VT: [bh][64][NPAD]; pads zero.
// Softmax: per-lane partial row-sums reduced across lanes once at the end;
// cross-lane max computed only inside the (rare) rescale branch.
__global__ __launch_bounds__(256) void flash_k(
    const u16* __restrict__ Q, const u16* __restrict__ K,
    const u16* __restrict__ VT, u16* __restrict__ obuf)
{
  const int lid = blockIdx.x;
  const int xcd = lid & 7, slot = lid >> 3;         // slot in [0,60)
  const int bh = xcd * 12 + slot / 5;
  const int qb = slot % 5;                          // 128-row q block
  const int b = bh / NHEAD, h = bh % NHEAD;
  const int tid = threadIdx.x, lane = tid & 63, w = tid >> 6;
  const int frow = lane & 15, quad = lane >> 4;
  __shared__ u16 P[4][2][16][80];
  const u16* Qb = Q  + (long long)bh * NPAD * HDIM;
  const u16* Kb = K  + (long long)bh * NPAD * HDIM;
  const u16* Vb = VT + (long long)bh * HDIM * NPAD;
  bf8 qa0[2], qa1[2];
  #pragma unroll
  for (int bd = 0; bd < 2; ++bd){
    const u16* qr = &Qb[(qb*128 + bd*64 + w*16 + frow)*HDIM + quad*8];
    qa0[bd] = *(const bf8*)qr;
    qa1[bd] = *(const bf8*)(qr + 32);
  }
  f4 o[2][4] = {};
  float m[2][4], lp[2][4];
  #pragma unroll
  for (int bd = 0; bd < 2; ++bd)
  #pragma unroll
  for (int j = 0; j < 4; ++j){ m[bd][j] = -1e30f; lp[bd][j] = 0.0f; }

  // K fragments for current tile (prefetched one tile ahead)
  bf8 kb0[4], kb1[4];
  #pragma unroll
  for (int n = 0; n < 4; ++n){
    const u16* kr = &Kb[(n*16 + frow)*HDIM + quad*8];
    kb0[n] = *(const bf8*)kr;
    kb1[n] = *(const bf8*)(kr + 32);
  }

  for (int kt = 0; kt < NPAD/64; ++kt){
    // V loads issued early (covered by softmax VALU)
    bf8 vb0[4], vb1[4];
    #pragma unroll
    for (int n = 0; n < 4; ++n){
      const u16* vr = &Vb[(n*16 + frow)*NPAD + kt*64 + quad*8];
      vb0[n] = *(const bf8*)vr;
      vb1[n] = *(const bf8*)(vr + 32);
    }
    // S = Q·K^T for both bands from shared K frags
    f4 s[2][4];
    __builtin_amdgcn_s_setprio(1);
    #pragma unroll
    for (int n = 0; n < 4; ++n)
    #pragma unroll
    for (int bd = 0; bd < 2; ++bd){
      f4 z = {};
      z        = __builtin_amdgcn_mfma_f32_16x16x32_bf16(qa0[bd], kb0[n], z, 0, 0, 0);
      s[bd][n] = __builtin_amdgcn_mfma_f32_16x16x32_bf16(qa1[bd], kb1[n], z, 0, 0, 0);
    }
    __builtin_amdgcn_s_setprio(0);
    // prefetch K for kt+1 (covered by softmax + PV)
    if (kt + 1 < NPAD/64){
      #pragma unroll
      for (int n = 0; n < 4; ++n){
        const u16* kr = &Kb[((kt+1)*64 + n*16 + frow)*HDIM + quad*8];
        kb0[n] = *(const bf8*)kr;
        kb1[n] = *(const bf8*)(kr + 32);
      }
    }
    if (kt == NPAD/64 - 1){                         // mask invalid k-cols
      #pragma unroll
      for (int n = 0; n < 4; ++n){
        int kcol = kt*64 + n*16 + frow;
        if (kcol >= NTOK){
          #pragma unroll
          for (int bd = 0; bd < 2; ++bd)
            s[bd][n][0] = s[bd][n][1] = s[bd][n][2] = s[bd][n][3] = -1e30f;
        }
      }
    }
    #pragma unroll
    for (int bd = 0; bd < 2; ++bd){
      // per-lane tile max; cross-lane reduce only if a rescale might be needed
      float vmax[4];
      int need = 0;
      #pragma unroll
      for (int j = 0; j < 4; ++j){
        vmax[j] = fmaxf(fmaxf(s[bd][0][j], s[bd][1][j]), fmaxf(s[bd][2][j], s[bd][3][j]));
        need |= (vmax[j] > m[bd][j] + 8.0f) ? 1 : 0;
      }
      if (__any(need)){                             // defer-max: rescale only on growth >8
        #pragma unroll
        for (int j = 0; j < 4; ++j){
          float v = vmax[j];
          v = fmaxf(v, __shfl_xor(v, 1));  v = fmaxf(v, __shfl_xor(v, 2));
          v = fmaxf(v, __shfl_xor(v, 4));  v = fmaxf(v, __shfl_xor(v, 8));
          float mn = fmaxf(m[bd][j], v);
          float sc = __expf(m[bd][j] - mn);
          m[bd][j] = mn;
          lp[bd][j] *= sc;                          // per-lane partial sum rescales too
          #pragma unroll
          for (int n = 0; n < 4; ++n) o[bd][n][j] *= sc;
        }
      }
      #pragma unroll
      for (int n = 0; n < 4; ++n){
        #pragma unroll
        for (int j = 0; j < 4; ++j){
          float p = __expf(s[bd][n][j] - m[bd][j]);   // bounded by e^8
          lp[bd][j] += p;                             // deferred cross-lane reduce
          P[w][bd][quad*4 + j][n*16 + frow] = f2b(p);
        }
      }
      bf8 pa0 = *(const bf8*)&P[w][bd][frow][quad*8];
      bf8 pa1 = *(const bf8*)&P[w][bd][frow][quad*8 + 32];
      __builtin_amdgcn_s_setprio(1);
      #pragma unroll
      for (int n = 0; n < 4; ++n){
        o[bd][n] = __builtin_amdgcn_mfma_f32_16x16x32_bf16(pa0, vb0[n], o[bd][n], 0, 0, 0);
        o[bd][n] = __builtin_amdgcn_mfma_f32_16x16x32_bf16(pa1, vb1[n], o[bd][n], 0, 0, 0);
      }
      __builtin_amdgcn_s_setprio(0);
    }
  }
  // final cross-lane reduce of the row sums (once, instead of per-kt)
  #pragma unroll
  for (int bd = 0; bd < 2; ++bd)
  #pragma unroll
  for (int j = 0; j < 4; ++j){
    float v = lp[bd][j];
    v += __shfl_xor(v, 1); v += __shfl_xor(v, 2);
    v += __shfl_xor(v, 4); v += __shfl_xor(v, 8);
    lp[bd][j] = v;
  }
  #pragma unroll
  for (int bd = 0; bd < 2; ++bd)
  #pragma unroll
  for (int j = 0; j < 4; ++j){
    int t = qb*128 + bd*64 + w*16 + quad*4 + j;
    if (t < NTOK){
      float inv = 1.0f / lp[bd][j];
      #pragma unroll
      for (int n = 0; n < 4; ++n)
        obuf[((long long)b*NTOK + t)*DIM + h*HDIM + n*16 + frow] = f2b(o[bd][n][j] * inv);
    }
  }
}

// LayerNorm over D=768 per row; writes bf16 (F32OUT=0) or f32 (F32OUT=1).
template<int F32OUT>
__global__ __launch_bounds__(256) void ln_k(const float* __restrict__ x,
    const float* __restrict__ s, const float* __restrict__ b,
    u16* __restrict__ ob, float* __restrict__ of)
{
  const long long row = blockIdx.x;
  const float* xr = x + row * DIM;
  const int t = threadIdx.x;
  float v0 = xr[t], v1 = xr[t + 256], v2 = xr[t + 512];
  float sum = v0 + v1 + v2;
  #pragma unroll
  for (int o = 32; o; o >>= 1) sum += __shfl_down(sum, o);
  __shared__ float r1[4], r2[4];
  const int lane = t & 63, w = t >> 6;
  if (lane == 0) r1[w] = sum;
  __syncthreads();
  float mu = (r1[0] + r1[1] + r1[2] + r1[3]) * (1.0f / DIM);
  float d0 = v0 - mu, d1 = v1 - mu, d2 = v2 - mu;
  float vs = d0*d0 + d1*d1 + d2*d2;
  #pragma unroll
  for (int o = 32; o; o >>= 1) vs += __shfl_down(vs, o);
  if (lane == 0) r2[w] = vs;
  __syncthreads();
  float inv = 1.0f / sqrtf((r2[0] + r2[1] + r2[2] + r2[3]) * (1.0f / DIM) + 1e-6f);
  if constexpr (F32OUT){
    float* orow = of + row * DIM;
    orow[t]       = d0 * inv * s[t]       + b[t];
    orow[t + 256] = d1 * inv * s[t + 256] + b[t + 256];
    orow[t + 512] = d2 * inv * s[t + 512] + b[t + 512];
  } else {
    u16* orow = ob + row * DIM;
    orow[t]       = f2b(d0 * inv * s[t]       + b[t]);
    orow[t + 256] = f2b(d1 * inv * s[t + 256] + b[t + 256]);
    orow[t + 512] = f2b(d2 * inv * s[t + 512] + b[t + 512]);
  }
}

__global__ void ropetab_k(const float* __restrict__ periods, float* __restrict__ tab)
{
  int idx = blockIdx.x * blockDim.x + threadIdx.x;
  if (idx >= 24 * 16) return;
  int c = idx >> 4, f = idx & 15;
  float fr = 6.283185307179586f / periods[f];
  float a = (float)c * fr;
  tab[idx]       = cosf(a);
  tab[384 + idx] = sinf(a);
}

__global__ void initx_k(float* __restrict__ x, const float* __restrict__ cls,
                        const float* __restrict__ stor)
{
  int idx = blockIdx.x * blockDim.x + threadIdx.x;
  if (idx >= BATCH * 5 * DIM) return;
  int d = idx % DIM; int t = (idx / DIM) % 5; int b = idx / (5 * DIM);
  x[((long long)b * NTOK + t) * DIM + d] = (t == 0) ? cls[d] : stor[(t - 1) * DIM + d];
}

__global__ void patch_k(const float* __restrict__ px, u16* __restrict__ Ap)
{
  int idx = blockIdx.x * blockDim.x + threadIdx.x;
  if (idx >= MCONV * DIM) return;
  int k = idx % DIM, m = idx / DIM;
  int b = m / 576, r = m % 576, hp = r / 24, wp = r % 24;
  int c = k / 256, rem = k % 256, p = rem / 16, q = rem % 16;
  float v = px[((((long long)b * 3 + c) * 384) + hp * 16 + p) * 384 + wp * 16 + q];
  Ap[idx] = f2b(v);
}

__global__ void cvt_k(const float* __restrict__ src, u16* __restrict__ dst, long long n)
{
  long long i = (long long)blockIdx.x * blockDim.x + threadIdx.x;
  long long stride = (long long)gridDim.x * blockDim.x;
  for (; i < n; i += stride) dst[i] = f2b(src[i]);
}

__global__ void biaseff_k(const float* __restrict__ qb, const float* __restrict__ bm,
                          float* __restrict__ out, int n)
{
  int i = blockIdx.x * blockDim.x + threadIdx.x;
  if (i < n) out[i] = qb[i] * bm[i];
}

extern "C" void kernel_launch(void* const* d_in, const int* in_sizes, int n_in,
                              void* d_out, int out_size, void* d_ws, size_t ws_size,
                              hipStream_t stream)
{
  const float* pixel   = (const float*)d_in[0];
  const float* conv_w  = (const float*)d_in[1];
  const float* conv_b  = (const float*)d_in[2];
  const float* cls     = (const float*)d_in[3];
  const float* stor    = (const float*)d_in[4];
  const float* periods = (const float*)d_in[5];
  const float* ln1s    = (const float*)d_in[6];
  const float* ln1b    = (const float*)d_in[7];
  const float* qkvw    = (const float*)d_in[8];
  const float* qkvb    = (const float*)d_in[9];
  const float* bmask   = (const float*)d_in[10];
  const float* projw   = (const float*)d_in[11];
  const float* projb   = (const float*)d_in[12];
  const float* ls1     = (const float*)d_in[13];
  const float* ln2s    = (const float*)d_in[14];
  const float* ln2b    = (const float*)d_in[15];
  const float* fc1w    = (const float*)d_in[16];
  const float* fc1b    = (const float*)d_in[17];
  const float* fc2w    = (const float*)d_in[18];
  const float* fc2b    = (const float*)d_in[19];
  const float* ls2     = (const float*)d_in[20];
  const float* lnfs    = (const float*)d_in[21];
  const float* lnfb    = (const float*)d_in[22];

  char* wsp = (char*)d_ws;
  auto alloc = [&](long long bytes) -> char* {
    char* p = wsp; wsp += (bytes + 255) & ~255LL; return p;
  };
  u16*   wqkv  = (u16*)  alloc((long long)NLAYER*2304*768*2);
  u16*   wproj = (u16*)  alloc((long long)NLAYER*768*768*2);
  u16*   wfc1  = (u16*)  alloc((long long)NLAYER*3072*768*2);
  u16*   wfc2  = (u16*)  alloc((long long)NLAYER*768*3072*2);
  u16*   wconv = (u16*)  alloc((long long)768*768*2);
  float* beff  = (float*)alloc((long long)NLAYER*2304*4);
  float* x     = (float*)alloc((long long)MPAD2*DIM*4);
  u16*   h     = (u16*)  alloc((long long)MPAD2*DIM*2);
  u16*   obuf  = (u16*)  alloc((long long)MPAD2*DIM*2);
  u16*   mlp   = (u16*)  alloc((long long)MPAD2*DFF*2);
  u16*   Ap    = (u16*)  alloc((long long)MCONV*DIM*2);
  u16*   Q     = (u16*)  alloc(QSZ*2*3);
  u16*   Kb    = Q + QSZ;
  u16*   VT    = Q + 2*QSZ;     // V stored transposed [bh][d][t]
  float* tab   = (float*)alloc((long long)2*24*16*4);
  if ((size_t)(wsp - (char*)d_ws) > ws_size) return;  // workspace too small

  auto cvt = [&](const float* src, u16* dst, long long n){
    long long nb = (n + 255) / 256; if (nb > 4096) nb = 4096;
    cvt_k<<<(int)nb, 256, 0, stream>>>(src, dst, n);
  };
  cvt(qkvw,  wqkv,  (long long)NLAYER*2304*768);
  cvt(projw, wproj, (long long)NLAYER*768*768);
  cvt(fc1w,  wfc1,  (long long)NLAYER*3072*768);
  cvt(fc2w,  wfc2,  (long long)NLAYER*768*3072);
  cvt(conv_w, wconv, (long long)768*768);
  biaseff_k<<<(NLAYER*2304 + 255)/256, 256, 0, stream>>>(qkvb, bmask, beff, NLAYER*2304);
  ropetab_k<<<2, 256, 0, stream>>>(periods, tab);
  hipMemsetAsync(Q, 0, (size_t)QSZ*2*3, stream);   // Q/K pad rows, VT pad cols zero

  patch_k<<<(MCONV*DIM + 255)/256, 256, 0, stream>>>(pixel, Ap);
  initx_k<<<(BATCH*5*DIM + 255)/256, 256, 0, stream>>>(x, cls, stor);
  gemmRS<EPI_CONV,64,64,4><<<dim3(DIM/64, MCONV/64), 256, 0, stream>>>(
      Ap, DIM, wconv, DIM, DIM, conv_b, nullptr, x, nullptr);

  for (int l = 0; l < NLAYER; ++l){
    ln_k<0><<<MTOK, 256, 0, stream>>>(x, ln1s + l*DIM, ln1b + l*DIM, h, nullptr);
    gemmRS<EPI_QKV,128,64,4><<<dim3(2304/64, MPAD2/128), 256, 0, stream>>>(
        h, DIM, wqkv + (long long)l*2304*768, DIM, DIM,
        beff + l*2304, tab, nullptr, Q);
    flash_k<<<dim3(480), 256, 0, stream>>>(Q, Kb, VT, obuf);
    gemmRS<EPI_PROJ,64,64,4><<<dim3(DIM/64, MPAD2/64), 256, 0, stream>>>(
        obuf, DIM, wproj + (long long)l*768*768, DIM, DIM,
        projb + l*DIM, ls1 + l*DIM, x, nullptr);
    ln_k<0><<<MTOK, 256, 0, stream>>>(x, ln2s + l*DIM, ln2b + l*DIM, h, nullptr);
    gemmRS<EPI_GELU,128,64,4><<<dim3(DFF/64, MPAD2/128), 256, 0, stream>>>(
        h, DIM, wfc1 + (long long)l*3072*768, DIM, DIM,
        fc1b + l*DFF, nullptr, nullptr, mlp);
    gemmRS<EPI_FC2,64,64,4><<<dim3(DIM/64, MPAD2/64), 256, 0, stream>>>(
        mlp, DFF, wfc2 + (long long)l*768*3072, DFF, DFF,
        fc2b + l*DIM, ls2 + l*DIM, x, nullptr);
  }
  ln_k<1><<<MTOK, 256, 0, stream>>>(x, lnfs, lnfb, nullptr, (float*)d_out);
}

// Round 23
// 3066.572 us; speedup vs baseline: 1.1491x; 1.0233x over previous
//
#include <hip/hip_runtime.h>
#include <math.h>

typedef unsigned short u16;
typedef __attribute__((ext_vector_type(8))) short bf8;     // 8 x bf16 (raw bits)
typedef __attribute__((ext_vector_type(4))) float f4;

#define DEV static __device__ __forceinline__

DEV u16 f2b(float f){
  unsigned u = __builtin_bit_cast(unsigned, f);
  u += 0x7fffu + ((u >> 16) & 1u);          // round-to-nearest-even
  return (u16)(u >> 16);
}
DEV float b2f(u16 h){
  unsigned u = ((unsigned)h) << 16;
  return __builtin_bit_cast(float, u);
}

#define BATCH  8
#define NTOK   581
#define NPAD   640
#define DIM    768
#define DFF    3072
#define NHEAD  12
#define HDIM   64
#define NLAYER 12
#define MTOK   (BATCH*NTOK)     /* 4648 */
#define MPAD2  4736             /* 37*128 = 74*64 */
#define MCONV  (BATCH*576)      /* 4608 = 72*64 */
#define ATTN_SCALE 0.125f
#define BHEADS (BATCH*NHEAD)    /* 96 */
#define QSZ    ((long long)BHEADS*NPAD*HDIM)

enum { EPI_CONV=0, EPI_QKV, EPI_PROJ, EPI_GELU, EPI_FC2 };

// bijective XCD-chunked swizzle (m204): contiguous tile ids cluster per XCD
DEV int xcdswz(int lin, int n){
  int q = n >> 3, r = n & 7;
  int x = lin & 7, o = lin >> 3;
  return (x < r ? x*(q+1) : r*(q+1) + (x - r)*q) + o;
}

// LDS index for [row][32] bf16 tiles, XOR-swizzled (round-5-verified: zero
// bank conflicts for 16x16 fragment reads): col ^= 16 elements when row&8.
DEV int lidx(int row, int col){
  return row*32 + (col ^ ((row & 8) ? 16 : 0));
}

// ---- BMxBN tile GEMM, BK=32, reg-staged dbuf, async-split, 1 barrier/K-step ----
// C = A(MxK,row) * B(NxK,row)^T. M = gridDim.y*BM, N = gridDim.x*BN, K%64==0.
// EPI_QKV: aux = rope table (cos[0:384], sin[384:768]); RoPE fused via lane-pair shfl.
template<int EPI, int BM, int BN, int NWAVE>
__global__ __launch_bounds__(NWAVE*64) void gemmRS(
    const u16* __restrict__ A, int lda,
    const u16* __restrict__ B, int ldb, int K,
    const float* __restrict__ bias,
    const float* __restrict__ aux,
    float* __restrict__ Cf,
    u16* __restrict__ Cb)
{
  constexpr int NT = NWAVE * 64;
  constexpr int SR = NT / 4;                        // staging rows per slot
  constexpr int AL = BM / SR, BL = BN / SR;         // loads per thread
  constexpr int WROWS = (NWAVE == 8) ? 4 : 2;
  constexpr int WCOLS = NWAVE / WROWS;
  constexpr int TR = BM / WROWS, TC = BN / WCOLS;   // wave output tile
  constexpr int MR = TR / 16, NR = TC / 16;
  const int gx = gridDim.x;
  const int lin = blockIdx.y * gx + blockIdx.x;
  const int tix = xcdswz(lin, gx * gridDim.y);
  const int bm = (tix / gx) * BM, bn = (tix % gx) * BN;
  __shared__ __attribute__((aligned(16))) u16 As[2][BM*32];
  __shared__ __attribute__((aligned(16))) u16 Bs[2][BN*32];
  const int tid  = threadIdx.x;
  const int lane = tid & 63, wid = tid >> 6;
  const int wr = wid % WROWS, wc = wid / WROWS;
  const int srow = tid >> 2, scol = (tid & 3) * 8;  // staging coords
  const u16* gA[AL]; const u16* gB[BL];
  #pragma unroll
  for (int i = 0; i < AL; ++i) gA[i] = A + (long long)(bm + i*SR + srow) * lda + scol;
  #pragma unroll
  for (int i = 0; i < BL; ++i) gB[i] = B + (long long)(bn + i*SR + srow) * ldb + scol;
  const int frow = lane & 15, quad = lane >> 4, fk = quad * 8;

  f4 acc[MR][NR] = {};
  const int T = K >> 5;                             // even (K%64==0)

  bf8 xA[AL], xB[BL], yA[AL], yB[BL];
  auto loadX = [&](int kt){
    #pragma unroll
    for (int i = 0; i < AL; ++i) xA[i] = *(const bf8*)(gA[i] + kt*32);
    #pragma unroll
    for (int i = 0; i < BL; ++i) xB[i] = *(const bf8*)(gB[i] + kt*32);
  };
  auto loadY = [&](int kt){
    #pragma unroll
    for (int i = 0; i < AL; ++i) yA[i] = *(const bf8*)(gA[i] + kt*32);
    #pragma unroll
    for (int i = 0; i < BL; ++i) yB[i] = *(const bf8*)(gB[i] + kt*32);
  };
  auto storeX = [&](int buf){
    #pragma unroll
    for (int i = 0; i < AL; ++i) *(bf8*)&As[buf][lidx(i*SR + srow, scol)] = xA[i];
    #pragma unroll
    for (int i = 0; i < BL; ++i) *(bf8*)&Bs[buf][lidx(i*SR + srow, scol)] = xB[i];
  };
  auto storeY = [&](int buf){
    #pragma unroll
    for (int i = 0; i < AL; ++i) *(bf8*)&As[buf][lidx(i*SR + srow, scol)] = yA[i];
    #pragma unroll
    for (int i = 0; i < BL; ++i) *(bf8*)&Bs[buf][lidx(i*SR + srow, scol)] = yB[i];
  };
  auto compute = [&](int buf){
    bf8 af[MR], bf[NR];
    #pragma unroll
    for (int m = 0; m < MR; ++m)
      af[m] = *(const bf8*)&As[buf][lidx(wr*TR + m*16 + frow, fk)];
    #pragma unroll
    for (int n = 0; n < NR; ++n)
      bf[n] = *(const bf8*)&Bs[buf][lidx(wc*TC + n*16 + frow, fk)];
    #pragma unroll
    for (int m = 0; m < MR; ++m)
    #pragma unroll
    for (int n = 0; n < NR; ++n)
      acc[m][n] = __builtin_amdgcn_mfma_f32_16x16x32_bf16(af[m], bf[n], acc[m][n], 0, 0, 0);
  };

  // prologue: tile0 -> X, tile1 -> Y, write tile0
  loadX(0); loadY(1);
  storeX(0);
  __syncthreads();

  for (int t = 0; t < T; t += 2){
    // even half: compute tile t (buf0); stage Y(t+1)->buf1; load X <- t+2
    if (t + 2 < T) loadX(t + 2);
    storeY(1);
    compute(0);
    __syncthreads();
    // odd half: compute tile t+1 (buf1); stage X(t+2)->buf0; load Y <- t+3
    if (t + 3 < T) loadY(t + 3);
    if (t + 2 < T) storeX(0);
    compute(1);
    __syncthreads();
  }

  #pragma unroll
  for (int mi = 0; mi < MR; ++mi)
  #pragma unroll
  for (int ni = 0; ni < NR; ++ni){
    f4 v = acc[mi][ni];
    int col = bn + wc*TC + ni*16 + frow;
    int r0  = bm + wr*TR + mi*16 + quad*4;
    #pragma unroll
    for (int j = 0; j < 4; ++j){
      int m = r0 + j;
      float val = v[j];
      if constexpr (EPI == EPI_CONV){
        int b = m / 576, p = m % 576;
        Cf[((long long)b*NTOK + 5 + p)*DIM + col] = val + bias[col];
      } else if constexpr (EPI == EPI_QKV){
        if (m < MTOK){                              // uniform across lane pairs
          int b = m / NTOK, tt = m % NTOK;
          int which = col / DIM, rem = col % DIM;
          int h = rem / HDIM, hd = rem % HDIM;
          float x = val + bias[col];
          if (which == 0) x *= ATTN_SCALE;          // scale commutes with rotation
          if (which < 2 && tt >= 5){                // fused RoPE (pair-uniform branch)
            float po = __shfl_xor(x, 1);            // partner of the (even,odd) pair
            int p = tt - 5;
            int f = (hd & 31) >> 1;
            int pc = (hd < 32) ? (p % 24) : (p / 24);
            float c = aux[pc*16 + f];
            float s = aux[384 + pc*16 + f];
            x = (hd & 1) ? (po*s + x*c) : (x*c - po*s);
          }
          long long bh = (long long)(b*NHEAD + h);
          if (which == 2)      // V stored transposed: VT[bh][d][t]
            Cb[2*QSZ + (bh*HDIM + hd)*NPAD + tt] = f2b(x);
          else
            Cb[(long long)which*QSZ + (bh*NPAD + tt)*HDIM + hd] = f2b(x);
        }
      } else if constexpr (EPI == EPI_PROJ || EPI == EPI_FC2){
        if (m < MTOK)
          Cf[(long long)m*DIM + col] += aux[col] * (val + bias[col]);
      } else if constexpr (EPI == EPI_GELU){
        float x = val + bias[col];
        float g = 0.5f * x * (1.0f + erff(x * 0.70710678118f));
        Cb[(long long)m*DFF + col] = f2b(g);
      }
    }
  }
}

// -------- flash attention: 128 q-rows of one (b,h) per block; 4 waves x 2 bands --------
// Grid: 1D 480 blocks; lid&7 = XCD (round-robin heuristic): 12 heads/XCD -> K/V 1.9MB L2-fits.
// Q,K: [bh][NPAD][64] bf16 (Q pre-scaled+roped); VT: [bh][64][NPAD]; pads zero.
// Softmax: per-lane partial row-sums reduced across lanes once at the end;
// cross-lane max computed only inside the (rare) rescale branch.
__global__ __launch_bounds__(256) void flash_k(
    const u16* __restrict__ Q, const u16* __restrict__ K,
    const u16* __restrict__ VT, u16* __restrict__ obuf)
{
  const int lid = blockIdx.x;
  const int xcd = lid & 7, slot = lid >> 3;         // slot in [0,60)
  const int bh = xcd * 12 + slot / 5;
  const int qb = slot % 5;                          // 128-row q block
  const int b = bh / NHEAD, h = bh % NHEAD;
  const int tid = threadIdx.x, lane = tid & 63, w = tid >> 6;
  const int frow = lane & 15, quad = lane >> 4;
  __shared__ u16 P[4][2][16][80];
  const u16* Qb = Q  + (long long)bh * NPAD * HDIM;
  const u16* Kb = K  + (long long)bh * NPAD * HDIM;
  const u16* Vb = VT + (long long)bh * HDIM * NPAD;
  bf8 qa0[2], qa1[2];
  #pragma unroll
  for (int bd = 0; bd < 2; ++bd){
    const u16* qr = &Qb[(qb*128 + bd*64 + w*16 + frow)*HDIM + quad*8];
    qa0[bd] = *(const bf8*)qr;
    qa1[bd] = *(const bf8*)(qr + 32);
  }
  f4 o[2][4] = {};
  float m[2][4], lp[2][4];
  #pragma unroll
  for (int bd = 0; bd < 2; ++bd)
  #pragma unroll
  for (int j = 0; j < 4; ++j){ m[bd][j] = -1e30f; lp[bd][j] = 0.0f; }

  // K fragments for current tile (prefetched one tile ahead)
  bf8 kb0[4], kb1[4];
  #pragma unroll
  for (int n = 0; n < 4; ++n){
    const u16* kr = &Kb[(n*16 + frow)*HDIM + quad*8];
    kb0[n] = *(const bf8*)kr;
    kb1[n] = *(const bf8*)(kr + 32);
  }

  for (int kt = 0; kt < NPAD/64; ++kt){
    // V loads issued early (covered by softmax VALU)
    bf8 vb0[4], vb1[4];
    #pragma unroll
    for (int n = 0; n < 4; ++n){
      const u16* vr = &Vb[(n*16 + frow)*NPAD + kt*64 + quad*8];
      vb0[n] = *(const bf8*)vr;
      vb1[n] = *(const bf8*)(vr + 32);
    }
    // S = Q·K^T for both bands from shared K frags
    f4 s[2][4];
    __builtin_amdgcn_s_setprio(1);
    #pragma unroll
    for (int n = 0; n < 4; ++n)
    #pragma unroll
    for (int bd = 0; bd < 2; ++bd){
      f4 z = {};
      z        = __builtin_amdgcn_mfma_f32_16x16x32_bf16(qa0[bd], kb0[n], z, 0, 0, 0);
      s[bd][n] = __builtin_amdgcn_mfma_f32_16x16x32_bf16(qa1[bd], kb1[n], z, 0, 0, 0);
    }
    __builtin_amdgcn_s_setprio(0);
    // prefetch K for kt+1 (covered by softmax + PV)
    if (kt + 1 < NPAD/64){
      #pragma unroll
      for (int n = 0; n < 4; ++n){
        const u16* kr = &Kb[((kt+1)*64 + n*16 + frow)*HDIM + quad*8];
        kb0[n] = *(const bf8*)kr;
        kb1[n] = *(const bf8*)(kr + 32);
      }
    }
    if (kt == NPAD/64 - 1){                         // mask invalid k-cols
      #pragma unroll
      for (int n = 0; n < 4; ++n){
        int kcol = kt*64 + n*16 + frow;
        if (kcol >= NTOK){
          #pragma unroll
          for (int bd = 0; bd < 2; ++bd)
            s[bd][n][0] = s[bd][n][1] = s[bd][n][2] = s[bd][n][3] = -1e30f;
        }
      }
    }
    #pragma unroll
    for (int bd = 0; bd < 2; ++bd){
      // per-lane tile max; cross-lane reduce only if a rescale might be needed
      float vmax[4];
      int need = 0;
      #pragma unroll
      for (int j = 0; j < 4; ++j){
        vmax[j] = fmaxf(fmaxf(s[bd][0][j], s[bd][1][j]), fmaxf(s[bd][2][j], s[bd][3][j]));
        need |= (vmax[j] > m[bd][j] + 8.0f) ? 1 : 0;
      }
      if (__any(need)){                             // defer-max: rescale only on growth >8
        #pragma unroll
        for (int j = 0; j < 4; ++j){
          float v = vmax[j];
          v = fmaxf(v, __shfl_xor(v, 1));  v = fmaxf(v, __shfl_xor(v, 2));
          v = fmaxf(v, __shfl_xor(v, 4));  v = fmaxf(v, __shfl_xor(v, 8));
          float mn = fmaxf(m[bd][j], v);
          float sc = __expf(m[bd][j] - mn);
          m[bd][j] = mn;
          lp[bd][j] *= sc;                          // per-lane partial sum rescales too
          #pragma unroll
          for (int n = 0; n < 4; ++n) o[bd][n][j] *= sc;
        }
      }
      #pragma unroll
      for (int n = 0; n < 4; ++n){
        #pragma unroll
        for (int j = 0; j < 4; ++j){
          float p = __expf(s[bd][n][j] - m[bd][j]);   // bounded by e^8
          lp[bd][j] += p;                             // deferred cross-lane reduce
          P[w][bd][quad*4 + j][n*16 + frow] = f2b(p);
        }
      }
      bf8 pa0 = *(const bf8*)&P[w][bd][frow][quad*8];
      bf8 pa1 = *(const bf8*)&P[w][bd][frow][quad*8 + 32];
      __builtin_amdgcn_s_setprio(1);
      #pragma unroll
      for (int n = 0; n < 4; ++n){
        o[bd][n] = __builtin_amdgcn_mfma_f32_16x16x32_bf16(pa0, vb0[n], o[bd][n], 0, 0, 0);
        o[bd][n] = __builtin_amdgcn_mfma_f32_16x16x32_bf16(pa1, vb1[n], o[bd][n], 0, 0, 0);
      }
      __builtin_amdgcn_s_setprio(0);
    }
  }
  // final cross-lane reduce of the row sums (once, instead of per-kt)
  #pragma unroll
  for (int bd = 0; bd < 2; ++bd)
  #pragma unroll
  for (int j = 0; j < 4; ++j){
    float v = lp[bd][j];
    v += __shfl_xor(v, 1); v += __shfl_xor(v, 2);
    v += __shfl_xor(v, 4); v += __shfl_xor(v, 8);
    lp[bd][j] = v;
  }
  #pragma unroll
  for (int bd = 0; bd < 2; ++bd)
  #pragma unroll
  for (int j = 0; j < 4; ++j){
    int t = qb*128 + bd*64 + w*16 + quad*4 + j;
    if (t < NTOK){
      float inv = 1.0f / lp[bd][j];
      #pragma unroll
      for (int n = 0; n < 4; ++n)
        obuf[((long long)b*NTOK + t)*DIM + h*HDIM + n*16 + frow] = f2b(o[bd][n][j] * inv);
    }
  }
}

// LayerNorm over D=768 per row; writes bf16 (F32OUT=0) or f32 (F32OUT=1).
template<int F32OUT>
__global__ __launch_bounds__(256) void ln_k(const float* __restrict__ x,
    const float* __restrict__ s, const float* __restrict__ b,
    u16* __restrict__ ob, float* __restrict__ of)
{
  const long long row = blockIdx.x;
  const float* xr = x + row * DIM;
  const int t = threadIdx.x;
  float v0 = xr[t], v1 = xr[t + 256], v2 = xr[t + 512];
  float sum = v0 + v1 + v2;
  #pragma unroll
  for (int o = 32; o; o >>= 1) sum += __shfl_down(sum, o);
  __shared__ float r1[4], r2[4];
  const int lane = t & 63, w = t >> 6;
  if (lane == 0) r1[w] = sum;
  __syncthreads();
  float mu = (r1[0] + r1[1] + r1[2] + r1[3]) * (1.0f / DIM);
  float d0 = v0 - mu, d1 = v1 - mu, d2 = v2 - mu;
  float vs = d0*d0 + d1*d1 + d2*d2;
  #pragma unroll
  for (int o = 32; o; o >>= 1) vs += __shfl_down(vs, o);
  if (lane == 0) r2[w] = vs;
  __syncthreads();
  float inv = 1.0f / sqrtf((r2[0] + r2[1] + r2[2] + r2[3]) * (1.0f / DIM) + 1e-6f);
  if constexpr (F32OUT){
    float* orow = of + row * DIM;
    orow[t]       = d0 * inv * s[t]       + b[t];
    orow[t + 256] = d1 * inv * s[t + 256] + b[t + 256];
    orow[t + 512] = d2 * inv * s[t + 512] + b[t + 512];
  } else {
    u16* orow = ob + row * DIM;
    orow[t]       = f2b(d0 * inv * s[t]       + b[t]);
    orow[t + 256] = f2b(d1 * inv * s[t + 256] + b[t + 256]);
    orow[t + 512] = f2b(d2 * inv * s[t + 512] + b[t + 512]);
  }
}

__global__ void ropetab_k(const float* __restrict__ periods, float* __restrict__ tab)
{
  int idx = blockIdx.x * blockDim.x + threadIdx.x;
  if (idx >= 24 * 16) return;
  int c = idx >> 4, f = idx & 15;
  float fr = 6.283185307179586f / periods[f];
  float a = (float)c * fr;
  tab[idx]       = cosf(a);
  tab[384 + idx] = sinf(a);
}

__global__ void initx_k(float* __restrict__ x, const float* __restrict__ cls,
                        const float* __restrict__ stor)
{
  int idx = blockIdx.x * blockDim.x + threadIdx.x;
  if (idx >= BATCH * 5 * DIM) return;
  int d = idx % DIM; int t = (idx / DIM) % 5; int b = idx / (5 * DIM);
  x[((long long)b * NTOK + t) * DIM + d] = (t == 0) ? cls[d] : stor[(t - 1) * DIM + d];
}

__global__ void patch_k(const float* __restrict__ px, u16* __restrict__ Ap)
{
  int idx = blockIdx.x * blockDim.x + threadIdx.x;
  if (idx >= MCONV * DIM) return;
  int k = idx % DIM, m = idx / DIM;
  int b = m / 576, r = m % 576, hp = r / 24, wp = r % 24;
  int c = k / 256, rem = k % 256, p = rem / 16, q = rem % 16;
  float v = px[((((long long)b * 3 + c) * 384) + hp * 16 + p) * 384 + wp * 16 + q];
  Ap[idx] = f2b(v);
}

__global__ void cvt_k(const float* __restrict__ src, u16* __restrict__ dst, long long n)
{
  long long i = (long long)blockIdx.x * blockDim.x + threadIdx.x;
  long long stride = (long long)gridDim.x * blockDim.x;
  for (; i < n; i += stride) dst[i] = f2b(src[i]);
}

__global__ void biaseff_k(const float* __restrict__ qb, const float* __restrict__ bm,
                          float* __restrict__ out, int n)
{
  int i = blockIdx.x * blockDim.x + threadIdx.x;
  if (i < n) out[i] = qb[i] * bm[i];
}

extern "C" void kernel_launch(void* const* d_in, const int* in_sizes, int n_in,
                              void* d_out, int out_size, void* d_ws, size_t ws_size,
                              hipStream_t stream)
{
  const float* pixel   = (const float*)d_in[0];
  const float* conv_w  = (const float*)d_in[1];
  const float* conv_b  = (const float*)d_in[2];
  const float* cls     = (const float*)d_in[3];
  const float* stor    = (const float*)d_in[4];
  const float* periods = (const float*)d_in[5];
  const float* ln1s    = (const float*)d_in[6];
  const float* ln1b    = (const float*)d_in[7];
  const float* qkvw    = (const float*)d_in[8];
  const float* qkvb    = (const float*)d_in[9];
  const float* bmask   = (const float*)d_in[10];
  const float* projw   = (const float*)d_in[11];
  const float* projb   = (const float*)d_in[12];
  const float* ls1     = (const float*)d_in[13];
  const float* ln2s    = (const float*)d_in[14];
  const float* ln2b    = (const float*)d_in[15];
  const float* fc1w    = (const float*)d_in[16];
  const float* fc1b    = (const float*)d_in[17];
  const float* fc2w    = (const float*)d_in[18];
  const float* fc2b    = (const float*)d_in[19];
  const float* ls2     = (const float*)d_in[20];
  const float* lnfs    = (const float*)d_in[21];
  const float* lnfb    = (const float*)d_in[22];

  char* wsp = (char*)d_ws;
  auto alloc = [&](long long bytes) -> char* {
    char* p = wsp; wsp += (bytes + 255) & ~255LL; return p;
  };
  u16*   wqkv  = (u16*)  alloc((long long)NLAYER*2304*768*2);
  u16*   wproj = (u16*)  alloc((long long)NLAYER*768*768*2);
  u16*   wfc1  = (u16*)  alloc((long long)NLAYER*3072*768*2);
  u16*   wfc2  = (u16*)  alloc((long long)NLAYER*768*3072*2);
  u16*   wconv = (u16*)  alloc((long long)768*768*2);
  float* beff  = (float*)alloc((long long)NLAYER*2304*4);
  float* x     = (float*)alloc((long long)MPAD2*DIM*4);
  u16*   h     = (u16*)  alloc((long long)MPAD2*DIM*2);
  u16*   obuf  = (u16*)  alloc((long long)MPAD2*DIM*2);
  u16*   mlp   = (u16*)  alloc((long long)MPAD2*DFF*2);
  u16*   Ap    = (u16*)  alloc((long long)MCONV*DIM*2);
  u16*   Q     = (u16*)  alloc(QSZ*2*3);
  u16*   Kb    = Q + QSZ;
  u16*   VT    = Q + 2*QSZ;     // V stored transposed [bh][d][t]
  float* tab   = (float*)alloc((long long)2*24*16*4);
  if ((size_t)(wsp - (char*)d_ws) > ws_size) return;  // workspace too small

  auto cvt = [&](const float* src, u16* dst, long long n){
    long long nb = (n + 255) / 256; if (nb > 4096) nb = 4096;
    cvt_k<<<(int)nb, 256, 0, stream>>>(src, dst, n);
  };
  cvt(qkvw,  wqkv,  (long long)NLAYER*2304*768);
  cvt(projw, wproj, (long long)NLAYER*768*768);
  cvt(fc1w,  wfc1,  (long long)NLAYER*3072*768);
  cvt(fc2w,  wfc2,  (long long)NLAYER*768*3072);
  cvt(conv_w, wconv, (long long)768*768);
  biaseff_k<<<(NLAYER*2304 + 255)/256, 256, 0, stream>>>(qkvb, bmask, beff, NLAYER*2304);
  ropetab_k<<<2, 256, 0, stream>>>(periods, tab);
  hipMemsetAsync(Q, 0, (size_t)QSZ*2*3, stream);   // Q/K pad rows, VT pad cols zero

  patch_k<<<(MCONV*DIM + 255)/256, 256, 0, stream>>>(pixel, Ap);
  initx_k<<<(BATCH*5*DIM + 255)/256, 256, 0, stream>>>(x, cls, stor);
  gemmRS<EPI_CONV,64,64,4><<<dim3(DIM/64, MCONV/64), 256, 0, stream>>>(
      Ap, DIM, wconv, DIM, DIM, conv_b, nullptr, x, nullptr);

  for (int l = 0; l < NLAYER; ++l){
    ln_k<0><<<MTOK, 256, 0, stream>>>(x, ln1s + l*DIM, ln1b + l*DIM, h, nullptr);
    gemmRS<EPI_QKV,128,64,4><<<dim3(2304/64, MPAD2/128), 256, 0, stream>>>(
        h, DIM, wqkv + (long long)l*2304*768, DIM, DIM,
        beff + l*2304, tab, nullptr, Q);
    flash_k<<<dim3(480), 256, 0, stream>>>(Q, Kb, VT, obuf);
    gemmRS<EPI_PROJ,64,64,4><<<dim3(DIM/64, MPAD2/64), 256, 0, stream>>>(
        obuf, DIM, wproj + (long long)l*768*768, DIM, DIM,
        projb + l*DIM, ls1 + l*DIM, x, nullptr);
    ln_k<0><<<MTOK, 256, 0, stream>>>(x, ln2s + l*DIM, ln2b + l*DIM, h, nullptr);
    gemmRS<EPI_GELU,128,64,4><<<dim3(DFF/64, MPAD2/128), 256, 0, stream>>>(
        h, DIM, wfc1 + (long long)l*3072*768, DIM, DIM,
        fc1b + l*DFF, nullptr, nullptr, mlp);
    gemmRS<EPI_FC2,64,64,4><<<dim3(DIM/64, MPAD2/64), 256, 0, stream>>>(
        mlp, DFF, wfc2 + (long long)l*768*3072, DFF, DFF,
        fc2b + l*DIM, ls2 + l*DIM, x, nullptr);
  }
  ln_k<1><<<MTOK, 256, 0, stream>>>(x, lnfs, lnfb, nullptr, (float*)d_out);
}